// Round 1
// baseline (2751.075 us; speedup 1.0000x reference)
//
#include <hip/hip_runtime.h>
#include <hip/hip_bf16.h>

typedef unsigned short u16;
typedef unsigned int u32;
typedef __attribute__((ext_vector_type(8))) short short8v;
typedef __attribute__((ext_vector_type(4))) float f32x4;
typedef __attribute__((ext_vector_type(8))) __bf16 bf16x8;

#define DEVINL static __device__ __forceinline__

DEVINL float bf2f(u16 h) { union { u32 u; float f; } c; c.u = ((u32)h) << 16; return c.f; }
DEVINL u16 f2bf(float f) {
  union { float f; u32 u; } c; c.f = f;
  u32 u = c.u;
  return (u16)((u + 0x7FFFu + ((u >> 16) & 1u)) >> 16);   // RNE
}

// ---------------------------------------------------------------- MFMA core
// NT fragment step: A-tile rows (M-dim) / B-tile rows (N-dim), both K-contig.
// LDS layout: row-major, XOR swizzle byte ^= (row&7)<<4 (G4 fix).
// Wave tile 64x32 (fr=4, fc=2), 16x16x32 bf16.
DEVINL void mfma_step(const u16* As, int aStrideB, int aRow0, int aKB,
                      const u16* Bs, int bRow0, int bKB,
                      int lane, f32x4 acc[4][2])
{
  const int lo = lane & 15, hi = (lane >> 4) * 16;
  bf16x8 av[4], bv[2];
#pragma unroll
  for (int fr = 0; fr < 4; ++fr) {
    int r = aRow0 + fr * 16 + lo;
    int byte = (r * aStrideB + aKB + hi) ^ ((r & 7) << 4);
    av[fr] = *(const bf16x8*)((const char*)As + byte);
  }
#pragma unroll
  for (int fc = 0; fc < 2; ++fc) {
    int r = bRow0 + fc * 16 + lo;
    int byte = (r * 128 + bKB + hi) ^ ((r & 7) << 4);
    bv[fc] = *(const bf16x8*)((const char*)Bs + byte);
  }
#pragma unroll
  for (int fr = 0; fr < 4; ++fr)
#pragma unroll
    for (int fc = 0; fc < 2; ++fc)
      acc[fr][fc] = __builtin_amdgcn_mfma_f32_16x16x32_bf16(av[fr], bv[fc], acc[fr][fc], 0, 0, 0);
}

// ------------------------------------------------- generic NT GEMM, 128x128 tile
// MODE 0: bf16 store to out0          (C = A*B^T)
// MODE 1: f32 store to out0 + blockIdx.z*2048*128 (split-K partials, K per split)
// MODE 2: x = acc + aux[row*ldc+col]; relu; f32->out0, bf16->out1
template<int MODE>
__global__ __launch_bounds__(512) void gemm_nt(const u16* __restrict__ A, const u16* __restrict__ B,
                                               void* __restrict__ out0, void* __restrict__ out1,
                                               const float* __restrict__ aux,
                                               int K, int lda, int ldb, int ldc)
{
  __shared__ u16 As[8192];
  __shared__ u16 Bs[8192];
  const int t = threadIdx.x;
  const int lane = t & 63, wid = t >> 6;
  const int wm = wid >> 2, wn = wid & 3;       // 2 x 4 waves
  const int bm = blockIdx.y * 128, bn = blockIdx.x * 128;
  const int kbase = blockIdx.z * K;

  const int off0 = t * 8, off1 = off0 + 4096;
  const int ar0 = off0 >> 6, ac0 = off0 & 63;
  const int ar1 = off1 >> 6, ac1 = off1 & 63;
  const size_t aRow0 = (size_t)(bm + ar0) * lda, aRow1 = (size_t)(bm + ar1) * lda;
  const size_t bRow0 = (size_t)(bn + ar0) * ldb, bRow1 = (size_t)(bn + ar1) * ldb;
  const int sA0 = (off0 * 2) ^ ((ar0 & 7) << 4);
  const int sA1 = (off1 * 2) ^ ((ar1 & 7) << 4);

  f32x4 acc[4][2] = {};
  short8v pa0 = *(const short8v*)(A + aRow0 + kbase + ac0);
  short8v pa1 = *(const short8v*)(A + aRow1 + kbase + ac1);
  short8v pb0 = *(const short8v*)(B + bRow0 + kbase + ac0);
  short8v pb1 = *(const short8v*)(B + bRow1 + kbase + ac1);

  for (int ks = 0; ks < K; ks += 64) {
    __syncthreads();
    *(short8v*)((char*)As + sA0) = pa0;
    *(short8v*)((char*)As + sA1) = pa1;
    *(short8v*)((char*)Bs + sA0) = pb0;
    *(short8v*)((char*)Bs + sA1) = pb1;
    __syncthreads();
    if (ks + 64 < K) {
      const int kn = kbase + ks + 64;
      pa0 = *(const short8v*)(A + aRow0 + kn + ac0);
      pa1 = *(const short8v*)(A + aRow1 + kn + ac1);
      pb0 = *(const short8v*)(B + bRow0 + kn + ac0);
      pb1 = *(const short8v*)(B + bRow1 + kn + ac1);
    }
#pragma unroll
    for (int kk = 0; kk < 2; ++kk)
      mfma_step(As, 128, wm * 64, kk * 64, Bs, wn * 32, kk * 64, lane, acc);
  }

#pragma unroll
  for (int fr = 0; fr < 4; ++fr)
#pragma unroll
    for (int fc = 0; fc < 2; ++fc)
#pragma unroll
      for (int r = 0; r < 4; ++r) {
        const int row = bm + wm * 64 + fr * 16 + (lane >> 4) * 4 + r;
        const int col = bn + wn * 32 + fc * 16 + (lane & 15);
        const float v = acc[fr][fc][r];
        if constexpr (MODE == 0) {
          ((u16*)out0)[(size_t)row * ldc + col] = f2bf(v);
        } else if constexpr (MODE == 1) {
          ((float*)out0)[(size_t)blockIdx.z * 262144 + (size_t)row * ldc + col] = v;
        } else {
          float x = v + aux[(size_t)row * ldc + col];
          x = fmaxf(x, 0.0f);
          ((float*)out0)[(size_t)row * ldc + col] = x;
          ((u16*)out1)[(size_t)row * ldc + col] = f2bf(x);
        }
      }
}

// ------------------------------------------------- small utility kernels
__global__ void k_init(float* scal) { if (threadIdx.x < 16) scal[threadIdx.x] = 0.0f; }

__global__ __launch_bounds__(256) void k_cvtH(const float* __restrict__ H, u16* __restrict__ Hb) {
  const int gid = blockIdx.x * 256 + threadIdx.x;
  for (int i = gid; i < 16777216; i += 1048576) {
    f32x4 f = *(const f32x4*)(H + (size_t)i * 4);
    uint2 o;
    o.x = (u32)f2bf(f[0]) | ((u32)f2bf(f[1]) << 16);
    o.y = (u32)f2bf(f[2]) | ((u32)f2bf(f[3]) << 16);
    *(uint2*)(Hb + (size_t)i * 4) = o;
  }
}

// C = W_ev @ W_ve (f32) + norm_XY = max abs row sum -> scal[0] (atomicMax, int-punned)
__global__ __launch_bounds__(256) void k_C(const float* __restrict__ Wev, const float* __restrict__ Wve,
                                           float* __restrict__ C, float* __restrict__ scal) {
  __shared__ float Wl[128 * 64];
  const int t = threadIdx.x;
  const int i = blockIdx.x * 16 + (t >> 4);
  const int jc = t & 15;
  float s[8];
#pragma unroll
  for (int e = 0; e < 8; ++e) s[e] = 0.f;
  for (int half = 0; half < 2; ++half) {
    __syncthreads();
    for (int idx = t; idx < 8192; idx += 256) {
      int k = idx >> 6, j = idx & 63;
      Wl[idx] = Wve[k * 128 + half * 64 + j];
    }
    __syncthreads();
    for (int k = 0; k < 128; ++k) {
      float a = Wev[i * 128 + k];
#pragma unroll
      for (int jj = 0; jj < 4; ++jj) s[half * 4 + jj] += a * Wl[k * 64 + jc + 16 * jj];
    }
  }
  float rs = 0.f;
#pragma unroll
  for (int half = 0; half < 2; ++half)
#pragma unroll
    for (int jj = 0; jj < 4; ++jj) {
      float v = s[half * 4 + jj];
      C[i * 128 + half * 64 + jc + 16 * jj] = v;
      rs += fabsf(v);
    }
#pragma unroll
  for (int d = 1; d < 16; d <<= 1) rs += __shfl_xor(rs, d);
  if (jc == 0) atomicMax((int*)scal, __float_as_int(rs));
}

__global__ void k_vinit(float* v0) {
  int i = blockIdx.x * 256 + threadIdx.x;
  if (i < 2048) {
    u32 u = (u32)i * 2654435761u;
    u ^= u >> 13; u *= 0x85EBCA6Bu; u ^= u >> 16;
    v0[i] = 0.5f + (float)(u & 0xFFFF) * (1.0f / 65536.0f);
  }
}

// vout = (M * vin) * scalef ; M bf16 2048x2048, grid 64 x 256
__global__ __launch_bounds__(256) void k_mv(const u16* __restrict__ M, const float* __restrict__ vin,
                                            float* __restrict__ vout, float scalef) {
  __shared__ float vs[2048];
  __shared__ float red[256];
  const int t = threadIdx.x, w = blockIdx.x;
  for (int i = t; i < 2048; i += 256) vs[i] = vin[i];
  __syncthreads();
  const int row = w * 32 + (t & 31);
  const int kb = t >> 5;
  const u16* mrow = M + (size_t)row * 2048 + kb * 256;
  float s = 0.f;
#pragma unroll 4
  for (int j = 0; j < 256; j += 8) {
    short8v h = *(const short8v*)(mrow + j);
#pragma unroll
    for (int e = 0; e < 8; ++e) s += bf2f((u16)h[e]) * vs[kb * 256 + j + e];
  }
  red[t] = s;
  __syncthreads();
  if (t < 32) {
    float y = 0.f;
#pragma unroll
    for (int q = 0; q < 8; ++q) y += red[t + q * 32];
    vout[w * 32 + t] = y * scalef;
  }
}

// Rayleigh on M (v, y=M v) -> pf, scale, scale^2
__global__ __launch_bounds__(256) void k_ray(const float* __restrict__ v, const float* __restrict__ y,
                                             float* __restrict__ scal) {
  __shared__ float rn[256], rd[256];
  const int t = threadIdx.x;
  float num = 0.f, den = 0.f;
  for (int i = t; i < 2048; i += 256) { float a = v[i], b = y[i]; num += a * b; den += a * a; }
  rn[t] = num; rd[t] = den;
  __syncthreads();
  for (int s = 128; s > 0; s >>= 1) {
    if (t < s) { rn[t] += rn[t + s]; rd[t] += rd[t + s]; }
    __syncthreads();
  }
  if (t == 0) {
    float lam = rn[0] / rd[0];          // pf estimate
    float kap = 0.99f / lam;
    float s2 = kap / scal[0];
    float sv = sqrtf(s2);
    if (!(sv < 1.0f)) { sv = 1.0f; s2 = 1.0f; }
    scal[1] = lam; scal[2] = sv; scal[3] = s2;
  }
}

__global__ void k_scaleA(const float* __restrict__ C, u16* __restrict__ Ab, const float* __restrict__ scal) {
  const float s2 = scal[3];
  const int i = blockIdx.x * 256 + threadIdx.x;   // grid 64
  Ab[i] = f2bf(s2 * C[i]);
}

// UT[p][m] = sum_q Wve[q][p] * E0[m][q]  (bf16 out, 128 x 32768)
__global__ __launch_bounds__(512) void k_UT(const float* __restrict__ Wve, const float* __restrict__ E0,
                                            u16* __restrict__ UT) {
  __shared__ u16 A2[128 * 128];   // WveT[p][q], row stride 256B
  __shared__ u16 Bs[8192];
  const int t = threadIdx.x, lane = t & 63, wid = t >> 6, wm = wid >> 2, wn = wid & 3;
  const int m0 = blockIdx.x * 128;
  for (int idx = t; idx < 16384; idx += 512) {
    int q = idx >> 7, p = idx & 127;           // p fastest -> coalesced global read
    int byte = (p * 256 + q * 2) ^ ((p & 7) << 4);
    *(u16*)((char*)A2 + byte) = f2bf(Wve[q * 128 + p]);
  }
  f32x4 acc[4][2] = {};
  const int off0 = t * 8, off1 = off0 + 4096;
  const int br0 = off0 >> 6, bc0 = off0 & 63, br1 = off1 >> 6, bc1 = off1 & 63;
  const int sB0 = (off0 * 2) ^ ((br0 & 7) << 4), sB1 = (off1 * 2) ^ ((br1 & 7) << 4);
  for (int k0 = 0; k0 < 128; k0 += 64) {
    __syncthreads();
    {
      const float* g0 = E0 + (size_t)(m0 + br0) * 128 + k0 + bc0;
      const float* g1 = E0 + (size_t)(m0 + br1) * 128 + k0 + bc1;
      f32x4 a0 = *(const f32x4*)g0, a1 = *(const f32x4*)(g0 + 4);
      f32x4 b0 = *(const f32x4*)g1, b1 = *(const f32x4*)(g1 + 4);
      short8v v0, v1;
#pragma unroll
      for (int e = 0; e < 4; ++e) {
        v0[e] = (short)f2bf(a0[e]); v0[4 + e] = (short)f2bf(a1[e]);
        v1[e] = (short)f2bf(b0[e]); v1[4 + e] = (short)f2bf(b1[e]);
      }
      *(short8v*)((char*)Bs + sB0) = v0;
      *(short8v*)((char*)Bs + sB1) = v1;
    }
    __syncthreads();
#pragma unroll
    for (int kk = 0; kk < 2; ++kk)
      mfma_step(A2, 256, wm * 64, k0 * 2 + kk * 64, Bs, wn * 32, kk * 64, lane, acc);
  }
#pragma unroll
  for (int fr = 0; fr < 4; ++fr)
#pragma unroll
    for (int fc = 0; fc < 2; ++fc)
#pragma unroll
      for (int r = 0; r < 4; ++r) {
        const int p = wm * 64 + fr * 16 + (lane >> 4) * 4 + r;
        const int m = m0 + wn * 32 + fc * 16 + (lane & 15);
        UT[(size_t)p * 32768 + m] = f2bf(acc[fr][fc][r]);
      }
}

// bT[n][p] = F0[p][n] + scale * sum_ks VP[ks][n][p]
__global__ __launch_bounds__(256) void k_bT(const float* __restrict__ F0, const float* __restrict__ VP,
                                            float* __restrict__ bT, const float* __restrict__ scal) {
  const float sc = scal[2];
  const int t = threadIdx.x;
  const int local = t * 8;
  const int nl = local >> 7, p = local & 127;
  const int n = blockIdx.x * 16 + nl;
  float sum[8];
#pragma unroll
  for (int e = 0; e < 8; ++e) sum[e] = 0.f;
  for (int ks = 0; ks < 16; ++ks) {
    const float* vp = VP + (size_t)ks * 262144 + (size_t)n * 128 + p;
    f32x4 a = *(const f32x4*)vp, b = *(const f32x4*)(vp + 4);
#pragma unroll
    for (int e = 0; e < 4; ++e) { sum[e] += a[e]; sum[4 + e] += b[e]; }
  }
  f32x4 o0, o1;
#pragma unroll
  for (int e = 0; e < 4; ++e) {
    o0[e] = F0[(size_t)(p + e) * 2048 + n] + sc * sum[e];
    o1[e] = F0[(size_t)(p + 4 + e) * 2048 + n] + sc * sum[4 + e];
  }
  *(f32x4*)(bT + (size_t)n * 128 + p) = o0;
  *(f32x4*)(bT + (size_t)n * 128 + p + 4) = o1;
}

// Xt = X0^T (f32 + bf16)
__global__ __launch_bounds__(256) void k_X0(const float* __restrict__ X0, float* __restrict__ Xtf,
                                            u16* __restrict__ Xtb) {
  __shared__ float sm[64][65];
  const int t = threadIdx.x;
  const int n0 = blockIdx.x * 64, p0 = blockIdx.y * 64;
  const int li = t >> 4, j4 = (t & 15) * 4;
  for (int ii = 0; ii < 64; ii += 16) {
    f32x4 v = *(const f32x4*)(X0 + (size_t)(p0 + li + ii) * 2048 + n0 + j4);
#pragma unroll
    for (int e = 0; e < 4; ++e) sm[li + ii][j4 + e] = v[e];
  }
  __syncthreads();
  for (int aa = 0; aa < 64; aa += 16) {
    const int a = li + aa;
    f32x4 o;
#pragma unroll
    for (int e = 0; e < 4; ++e) o[e] = sm[j4 + e][a];
    const size_t base = (size_t)(n0 + a) * 128 + p0 + j4;
    *(f32x4*)(Xtf + base) = o;
    uint2 h;
    h.x = (u32)f2bf(o[0]) | ((u32)f2bf(o[1]) << 16);
    h.y = (u32)f2bf(o[2]) | ((u32)f2bf(o[3]) << 16);
    *(uint2*)(Xtb + base) = h;
  }
}

// Ft = Xtf^T -> d_out
__global__ __launch_bounds__(256) void k_Ft(const float* __restrict__ Xtf, float* __restrict__ Ft) {
  __shared__ float sm[64][65];
  const int t = threadIdx.x;
  const int n0 = blockIdx.x * 64, p0 = blockIdx.y * 64;
  const int li = t >> 4, j4 = (t & 15) * 4;
  for (int ii = 0; ii < 64; ii += 16) {
    f32x4 v = *(const f32x4*)(Xtf + (size_t)(n0 + li + ii) * 128 + p0 + j4);
#pragma unroll
    for (int e = 0; e < 4; ++e) sm[li + ii][j4 + e] = v[e];
  }
  __syncthreads();
  for (int aa = 0; aa < 64; aa += 16) {
    const int a = li + aa;
    f32x4 o;
#pragma unroll
    for (int e = 0; e < 4; ++e) o[e] = sm[j4 + e][a];
    *(f32x4*)(Ft + (size_t)(p0 + a) * 2048 + n0 + j4) = o;
  }
}

// GT[q][n] = scale * sum_p Wev[p][q] * Xtb[n][p]   (bf16 out, 128 x 2048)
__global__ __launch_bounds__(512) void k_G(const float* __restrict__ Wev, const u16* __restrict__ Xtb,
                                           u16* __restrict__ GT, const float* __restrict__ scal) {
  __shared__ u16 A2[128 * 128];   // WevT[q][p]
  __shared__ u16 Bs[8192];
  const int t = threadIdx.x, lane = t & 63, wid = t >> 6, wm = wid >> 2, wn = wid & 3;
  const int n0 = blockIdx.x * 128;
  const float sc = scal[2];
  for (int idx = t; idx < 16384; idx += 512) {
    int p = idx >> 7, q = idx & 127;          // q fastest -> coalesced global read
    int byte = (q * 256 + p * 2) ^ ((q & 7) << 4);
    *(u16*)((char*)A2 + byte) = f2bf(Wev[p * 128 + q]);
  }
  f32x4 acc[4][2] = {};
  const int off0 = t * 8, off1 = off0 + 4096;
  const int br0 = off0 >> 6, bc0 = off0 & 63, br1 = off1 >> 6, bc1 = off1 & 63;
  const int sB0 = (off0 * 2) ^ ((br0 & 7) << 4), sB1 = (off1 * 2) ^ ((br1 & 7) << 4);
  for (int k0 = 0; k0 < 128; k0 += 64) {
    short8v pb0 = *(const short8v*)(Xtb + (size_t)(n0 + br0) * 128 + k0 + bc0);
    short8v pb1 = *(const short8v*)(Xtb + (size_t)(n0 + br1) * 128 + k0 + bc1);
    __syncthreads();
    *(short8v*)((char*)Bs + sB0) = pb0;
    *(short8v*)((char*)Bs + sB1) = pb1;
    __syncthreads();
#pragma unroll
    for (int kk = 0; kk < 2; ++kk)
      mfma_step(A2, 256, wm * 64, k0 * 2 + kk * 64, Bs, wn * 32, kk * 64, lane, acc);
  }
#pragma unroll
  for (int fr = 0; fr < 4; ++fr)
#pragma unroll
    for (int fc = 0; fc < 2; ++fc)
#pragma unroll
      for (int r = 0; r < 4; ++r) {
        const int q = wm * 64 + fr * 16 + (lane >> 4) * 4 + r;
        const int n = n0 + wn * 32 + fc * 16 + (lane & 15);
        GT[(size_t)q * 2048 + n] = f2bf(sc * acc[fr][fc][r]);
      }
}

// Et[m][q] = sum_n Hb[n][m] * GT[q][n]  (f32 out 32768 x 128); A transposed-staged via u32 pairing
__global__ __launch_bounds__(512) void k_Et(const u16* __restrict__ Hb, const u16* __restrict__ GT,
                                            float* __restrict__ Et) {
  __shared__ u16 As[8192];
  __shared__ u16 Bs[8192];
  const int t = threadIdx.x, lane = t & 63, wid = t >> 6, wm = wid >> 2, wn = wid & 3;
  const int m0 = blockIdx.y * 128;
  const int rp = t >> 4, mc = t & 15;
  const int off0 = t * 8, off1 = off0 + 4096;
  const int br0 = off0 >> 6, bc0 = off0 & 63, br1 = off1 >> 6, bc1 = off1 & 63;
  const int sB0 = (off0 * 2) ^ ((br0 & 7) << 4), sB1 = (off1 * 2) ^ ((br1 & 7) << 4);
  f32x4 acc[4][2] = {};
  short8v ra0 = *(const short8v*)(Hb + (size_t)(2 * rp) * 32768 + m0 + mc * 8);
  short8v ra1 = *(const short8v*)(Hb + (size_t)(2 * rp + 1) * 32768 + m0 + mc * 8);
  short8v pb0 = *(const short8v*)(GT + (size_t)br0 * 2048 + bc0);
  short8v pb1 = *(const short8v*)(GT + (size_t)br1 * 2048 + bc1);
  for (int k0 = 0; k0 < 2048; k0 += 64) {
    __syncthreads();
#pragma unroll
    for (int j = 0; j < 8; ++j) {
      const int m = mc * 8 + j;
      u32 wv = (u32)(u16)ra0[j] | ((u32)(u16)ra1[j] << 16);
      const int byte = (m * 128 + rp * 4) ^ ((m & 7) << 4);
      *(u32*)((char*)As + byte) = wv;
    }
    *(short8v*)((char*)Bs + sB0) = pb0;
    *(short8v*)((char*)Bs + sB1) = pb1;
    __syncthreads();
    if (k0 + 64 < 2048) {
      const int kn = k0 + 64;
      ra0 = *(const short8v*)(Hb + (size_t)(kn + 2 * rp) * 32768 + m0 + mc * 8);
      ra1 = *(const short8v*)(Hb + (size_t)(kn + 2 * rp + 1) * 32768 + m0 + mc * 8);
      pb0 = *(const short8v*)(GT + (size_t)br0 * 2048 + kn + bc0);
      pb1 = *(const short8v*)(GT + (size_t)br1 * 2048 + kn + bc1);
    }
#pragma unroll
    for (int kk = 0; kk < 2; ++kk)
      mfma_step(As, 128, wm * 64, kk * 64, Bs, wn * 32, kk * 64, lane, acc);
  }
#pragma unroll
  for (int fr = 0; fr < 4; ++fr)
#pragma unroll
    for (int fc = 0; fc < 2; ++fc)
#pragma unroll
      for (int r = 0; r < 4; ++r) {
        const int m = m0 + wm * 64 + fr * 16 + (lane >> 4) * 4 + r;
        const int q = wn * 32 + fc * 16 + (lane & 15);
        Et[(size_t)m * 128 + q] = acc[fr][fc][r];
      }
}

// ---------------------------------------------------------------- host
static constexpr size_t OFF_HB = 0;                         // 2048*32768 bf16 = 128 MiB
static constexpr size_t OFF_MB = 134217728;                 // 2048^2 bf16
static constexpr size_t OFF_M2 = OFF_MB + 8388608;
static constexpr size_t OFF_M4 = OFF_M2 + 8388608;
static constexpr size_t OFF_UT = OFF_M4 + 8388608;          // 128*32768 bf16
static constexpr size_t OFF_VP = OFF_UT + 8388608;          // 16*2048*128 f32
static constexpr size_t OFF_BT = OFF_VP + 16777216;         // 2048*128 f32
static constexpr size_t OFF_C  = OFF_BT + 1048576;          // 128^2 f32
static constexpr size_t OFF_AB = OFF_C + 65536;             // 128^2 bf16
static constexpr size_t OFF_ZT = OFF_AB + 32768;            // 128*2048 bf16
static constexpr size_t OFF_XF = OFF_ZT + 524288;           // 2048*128 f32
static constexpr size_t OFF_XB = OFF_XF + 1048576;          // 2048*128 bf16
static constexpr size_t OFF_GT = OFF_XB + 524288;           // 128*2048 bf16
static constexpr size_t OFF_V0 = OFF_GT + 524288;
static constexpr size_t OFF_V1 = OFF_V0 + 8192;
static constexpr size_t OFF_SC = OFF_V1 + 8192;             // total ~180 MiB

extern "C" void kernel_launch(void* const* d_in, const int* in_sizes, int n_in,
                              void* d_out, int out_size, void* d_ws, size_t ws_size,
                              hipStream_t stream) {
  (void)in_sizes; (void)n_in; (void)out_size; (void)ws_size;
  const float* X0  = (const float*)d_in[0];
  const float* H   = (const float*)d_in[1];
  const float* E0  = (const float*)d_in[2];
  const float* F0  = (const float*)d_in[3];
  const float* Wev = (const float*)d_in[4];
  const float* Wve = (const float*)d_in[5];
  float* out = (float*)d_out;
  char* ws = (char*)d_ws;

  u16* Hb   = (u16*)(ws + OFF_HB);
  u16* Mb   = (u16*)(ws + OFF_MB);
  u16* M2b  = (u16*)(ws + OFF_M2);
  u16* M4b  = (u16*)(ws + OFF_M4);
  u16* UTb  = (u16*)(ws + OFF_UT);
  float* VPp = (float*)(ws + OFF_VP);
  float* BTp = (float*)(ws + OFF_BT);
  float* Cws = (float*)(ws + OFF_C);
  u16* Ab   = (u16*)(ws + OFF_AB);
  u16* ZTp  = (u16*)(ws + OFF_ZT);
  float* Xtf = (float*)(ws + OFF_XF);
  u16* Xtb  = (u16*)(ws + OFF_XB);
  u16* GTp  = (u16*)(ws + OFF_GT);
  float* V0p = (float*)(ws + OFF_V0);
  float* V1p = (float*)(ws + OFF_V1);
  float* Scal = (float*)(ws + OFF_SC);

  k_init<<<1, 64, 0, stream>>>(Scal);
  k_cvtH<<<4096, 256, 0, stream>>>(H, Hb);

  // M = H H^T (bf16), then M^2, M^4 for fast power iteration
  gemm_nt<0><<<dim3(16, 16, 1), 512, 0, stream>>>(Hb, Hb, Mb, nullptr, nullptr, 32768, 32768, 32768, 2048);
  k_C<<<8, 256, 0, stream>>>(Wev, Wve, Cws, Scal);
  gemm_nt<0><<<dim3(16, 16, 1), 512, 0, stream>>>(Mb, Mb, M2b, nullptr, nullptr, 2048, 2048, 2048, 2048);
  gemm_nt<0><<<dim3(16, 16, 1), 512, 0, stream>>>(M2b, M2b, M4b, nullptr, nullptr, 2048, 2048, 2048, 2048);

  // power iteration: 45 matvecs on M^4 (effective power 180), Rayleigh on M
  k_vinit<<<8, 256, 0, stream>>>(V0p);
  float* va = V0p; float* vb = V1p;
  for (int i = 0; i < 45; ++i) {
    k_mv<<<64, 256, 0, stream>>>(M4b, va, vb, 0x1p-63f);
    float* tp = va; va = vb; vb = tp;
  }
  k_mv<<<64, 256, 0, stream>>>(Mb, va, vb, 1.0f);
  k_ray<<<1, 256, 0, stream>>>(va, vb, Scal);

  // A = scale^2 * (Wev Wve); b^T = F0^T + scale * H (E0 Wve0)
  k_scaleA<<<64, 256, 0, stream>>>(Cws, Ab, Scal);
  k_UT<<<256, 512, 0, stream>>>(Wve, E0, UTb);
  gemm_nt<1><<<dim3(1, 16, 16), 512, 0, stream>>>(Hb, UTb, (void*)VPp, nullptr, nullptr, 2048, 32768, 32768, 128);
  k_bT<<<128, 256, 0, stream>>>(F0, VPp, BTp, Scal);

  // DEQ loop: Xt' = relu(M (Xt A^T) + b^T), 50 iters
  k_X0<<<dim3(32, 2, 1), 256, 0, stream>>>(X0, Xtf, Xtb);
  for (int it = 0; it < 50; ++it) {
    gemm_nt<0><<<dim3(16, 1, 1), 512, 0, stream>>>(Ab, Xtb, ZTp, nullptr, nullptr, 128, 128, 128, 2048);
    gemm_nt<2><<<dim3(1, 16, 1), 512, 0, stream>>>(Mb, ZTp, (void*)Xtf, (void*)Xtb, BTp, 2048, 2048, 2048, 128);
  }

  // outputs
  k_G<<<16, 512, 0, stream>>>(Wev, Xtb, GTp, Scal);
  k_Ft<<<dim3(32, 2, 1), 256, 0, stream>>>(Xtf, out);
  k_Et<<<dim3(1, 256, 1), 512, 0, stream>>>(Hb, GTp, out + 262144);
}